// Round 7
// baseline (1122.526 us; speedup 1.0000x reference)
//
#include <hip/hip_runtime.h>

#define N_NODES 100000
#define N_EDGES 1600000
#define N_FEAT  256
#define N_HID   64
#define N_CLS   16
#define NB      391          // ceil(N_NODES/256) row buckets
#define CHUNK   8192         // edges per scatter block

typedef unsigned short bfraw;

__device__ __forceinline__ bfraw f2bf(float f) {   // RNE
    union { float f; unsigned int i; } v; v.f = f;
    unsigned int x = v.i;
    return (bfraw)((x + 0x7FFFu + ((x >> 16) & 1u)) >> 16);
}
__device__ __forceinline__ float bf2f(bfraw u) {
    union { unsigned int i; float f; } v; v.i = ((unsigned int)u) << 16; return v.f;
}

// ---------------------------------------------------------------------------
// GEMM1: h0[100000][64](bf16) = x[100000][256] @ W1[256][64] + b1
// ---------------------------------------------------------------------------
__global__ __launch_bounds__(256) void gemm1_k(const float* __restrict__ x,
                                               const float* __restrict__ W1,
                                               const float* __restrict__ b1,
                                               bfraw* __restrict__ h0) {
    __shared__ float As[16][64];   // [k][m]
    __shared__ float Bs[16][64];   // [k][n]
    const int bm  = blockIdx.x * 64;
    const int tid = threadIdx.x;
    const int tx = tid & 15;       // n/4
    const int ty = tid >> 4;       // m/4
    const int a_row = tid >> 2;
    const int a_k   = (tid & 3) * 4;
    const int b_k = tid >> 4;
    const int b_n = (tid & 15) * 4;

    const int  arow_g = bm + a_row;
    const bool a_ok   = arow_g < N_NODES;

    float acc[4][4] = {};

    for (int k0 = 0; k0 < N_FEAT; k0 += 16) {
        float4 ar = make_float4(0.f, 0.f, 0.f, 0.f);
        if (a_ok) ar = *(const float4*)(x + (size_t)arow_g * N_FEAT + k0 + a_k);
        float4 br = *(const float4*)(W1 + (size_t)(k0 + b_k) * N_HID + b_n);

        As[a_k + 0][a_row] = ar.x;
        As[a_k + 1][a_row] = ar.y;
        As[a_k + 2][a_row] = ar.z;
        As[a_k + 3][a_row] = ar.w;
        *(float4*)&Bs[b_k][b_n] = br;
        __syncthreads();

        #pragma unroll
        for (int kk = 0; kk < 16; ++kk) {
            float4 av = *(const float4*)&As[kk][ty * 4];
            float4 bv = *(const float4*)&Bs[kk][tx * 4];
            float a[4] = {av.x, av.y, av.z, av.w};
            float b[4] = {bv.x, bv.y, bv.z, bv.w};
            #pragma unroll
            for (int i = 0; i < 4; ++i)
                #pragma unroll
                for (int j = 0; j < 4; ++j)
                    acc[i][j] += a[i] * b[j];
        }
        __syncthreads();
    }

    float bb[4];
    #pragma unroll
    for (int j = 0; j < 4; ++j) bb[j] = b1[tx * 4 + j];

    #pragma unroll
    for (int i = 0; i < 4; ++i) {
        int row = bm + ty * 4 + i;
        if (row < N_NODES) {
            ushort4 o;
            o.x = f2bf(acc[i][0] + bb[0]);
            o.y = f2bf(acc[i][1] + bb[1]);
            o.z = f2bf(acc[i][2] + bb[2]);
            o.w = f2bf(acc[i][3] + bb[3]);
            *(ushort4*)(h0 + (size_t)row * N_HID + tx * 4) = o;
        }
    }
}

// ---------------------------------------------------------------------------
// Bucket histogram (row>>8), LDS-staged
// ---------------------------------------------------------------------------
__global__ __launch_bounds__(256) void hist_k(const int* __restrict__ rowi,
                                              int* __restrict__ bcnt) {
    __shared__ int lh[NB];
    for (int i = threadIdx.x; i < NB; i += 256) lh[i] = 0;
    __syncthreads();
    for (int e = blockIdx.x * 256 + threadIdx.x; e < N_EDGES; e += gridDim.x * 256)
        atomicAdd(&lh[rowi[e] >> 8], 1);
    __syncthreads();
    for (int i = threadIdx.x; i < NB; i += 256) {
        int c = lh[i];
        if (c) atomicAdd(&bcnt[i], c);
    }
}

// exclusive scan of 391 bucket counts -> bbase[0..NB], cursors
__global__ __launch_bounds__(512) void bscan_k(const int* __restrict__ bcnt,
                                               int* __restrict__ bbase,
                                               int* __restrict__ gcur) {
    __shared__ int s[512];
    int t = threadIdx.x;
    int v = (t < NB) ? bcnt[t] : 0;
    s[t] = v;
    __syncthreads();
    #pragma unroll
    for (int off = 1; off < 512; off <<= 1) {
        int x = (t >= off) ? s[t - off] : 0;
        __syncthreads();
        s[t] += x;
        __syncthreads();
    }
    if (t <= NB) {
        int b = s[t] - v;              // exclusive prefix (v=0 for t==NB)
        bbase[t] = b;
        if (t < NB) gcur[t] = b;
    }
}

// ---------------------------------------------------------------------------
// Scatter edges into bucket regions as packed int2 (col | rowlow<<17, val)
// ---------------------------------------------------------------------------
__global__ __launch_bounds__(256) void scatter_k(const int* __restrict__ rowi,
                                                 const int* __restrict__ coli,
                                                 const float* __restrict__ vals,
                                                 int* __restrict__ gcur,
                                                 int2* __restrict__ edges) {
    __shared__ int lh[NB];
    __shared__ int lb[NB];
    const int t  = threadIdx.x;
    const int e0 = blockIdx.x * CHUNK;
    for (int i = t; i < NB; i += 256) lh[i] = 0;
    __syncthreads();
    for (int j = t; j < CHUNK; j += 256) {
        int e = e0 + j;
        if (e < N_EDGES) atomicAdd(&lh[rowi[e] >> 8], 1);
    }
    __syncthreads();
    for (int i = t; i < NB; i += 256) {
        int c = lh[i];
        lb[i] = c ? atomicAdd(&gcur[i], c) : 0;
        lh[i] = 0;                      // reuse as rank counter
    }
    __syncthreads();
    for (int j = t; j < CHUNK; j += 256) {
        int e = e0 + j;
        if (e < N_EDGES) {
            int r  = rowi[e];
            int b  = r >> 8;
            int rk = atomicAdd(&lh[b], 1);
            edges[lb[b] + rk] = make_int2(coli[e] | ((r & 255) << 17),
                                          __float_as_int(vals[e]));
        }
    }
}

// ---------------------------------------------------------------------------
// SpMM1 per bucket: 64KB LDS acc[256 rows][64 feats], wave-per-edge.
// ---------------------------------------------------------------------------
__global__ __launch_bounds__(512) void spmm1_b_k(const int* __restrict__ bbase,
                                                 const int2* __restrict__ edges,
                                                 const bfraw* __restrict__ h0,
                                                 float* __restrict__ h1) {
    __shared__ float acc[256 * 64];    // 64 KB
    const int t = threadIdx.x;
    for (int i = t * 4; i < 256 * 64; i += 512 * 4)
        *(float4*)&acc[i] = make_float4(0.f, 0.f, 0.f, 0.f);
    __syncthreads();

    const int b    = blockIdx.x;
    const int beg  = bbase[b];
    const int n    = bbase[b + 1] - beg;
    const int lane = t & 63;
    const int w    = t >> 6;            // 8 waves
    const int nmain = n & ~31;

    for (int base = w * 4; base < nmain; base += 32) {
        int2 E[4];
        #pragma unroll
        for (int u = 0; u < 4; ++u) E[u] = edges[beg + base + u];
        float g[4];
        #pragma unroll
        for (int u = 0; u < 4; ++u)
            g[u] = bf2f(h0[(size_t)(E[u].x & 0x1FFFF) * N_HID + lane]);
        #pragma unroll
        for (int u = 0; u < 4; ++u)
            atomicAdd(&acc[((E[u].x >> 17) << 6) + lane],
                      __int_as_float(E[u].y) * g[u]);
    }
    for (int j = nmain + w; j < n; j += 8) {
        int2 E = edges[beg + j];
        float g = bf2f(h0[(size_t)(E.x & 0x1FFFF) * N_HID + lane]);
        atomicAdd(&acc[((E.x >> 17) << 6) + lane], __int_as_float(E.y) * g);
    }
    __syncthreads();

    const int row0 = b << 8;
    const int nf   = min(256, N_NODES - row0) * N_HID;
    for (int i = t * 4; i < nf; i += 512 * 4)
        *(float4*)(h1 + (size_t)row0 * N_HID + i) = *(float4*)&acc[i];
}

// ---------------------------------------------------------------------------
// GEMM2 fused with ReLU: h2[100000][16] = relu(h1) @ W2 + b2   (fp32)
// ---------------------------------------------------------------------------
__global__ __launch_bounds__(256) void gemm2_k(const float* __restrict__ h1,
                                               const float* __restrict__ W2,
                                               const float* __restrict__ b2,
                                               float* __restrict__ h2) {
    __shared__ float Hs[64][65];
    __shared__ float Ws[64 * 16];
    __shared__ float bs[16];
    const int bn  = blockIdx.x * 64;
    const int tid = threadIdx.x;

    *(float4*)&Ws[tid * 4] = *(const float4*)(W2 + tid * 4);
    if (tid < 16) bs[tid] = b2[tid];

    #pragma unroll
    for (int i = 0; i < 4; ++i) {
        int idx  = tid + i * 256;
        int node = idx >> 4;
        int c4   = idx & 15;
        int nr   = bn + node;
        float4 hv = make_float4(0.f, 0.f, 0.f, 0.f);
        if (nr < N_NODES) hv = *(const float4*)(h1 + (size_t)nr * N_HID + c4 * 4);
        Hs[node][c4 * 4 + 0] = fmaxf(hv.x, 0.f);
        Hs[node][c4 * 4 + 1] = fmaxf(hv.y, 0.f);
        Hs[node][c4 * 4 + 2] = fmaxf(hv.z, 0.f);
        Hs[node][c4 * 4 + 3] = fmaxf(hv.w, 0.f);
    }
    __syncthreads();

    const int node = tid >> 2;
    const int c0   = (tid & 3) * 4;
    float a0 = bs[c0 + 0], a1 = bs[c0 + 1], a2 = bs[c0 + 2], a3 = bs[c0 + 3];
    #pragma unroll
    for (int k = 0; k < 64; ++k) {
        float hval = Hs[node][k];
        a0 += hval * Ws[k * 16 + c0 + 0];
        a1 += hval * Ws[k * 16 + c0 + 1];
        a2 += hval * Ws[k * 16 + c0 + 2];
        a3 += hval * Ws[k * 16 + c0 + 3];
    }
    int nr = bn + node;
    if (nr < N_NODES)
        *(float4*)(h2 + (size_t)nr * N_CLS + c0) = make_float4(a0, a1, a2, a3);
}

// ---------------------------------------------------------------------------
// SpMM2 per bucket + fused log_softmax. acc stride 17 (bank-conflict pad).
// 16 lanes per edge, 4 edges per wave, 4 waves.
// ---------------------------------------------------------------------------
__global__ __launch_bounds__(256) void spmm2_b_k(const int* __restrict__ bbase,
                                                 const int2* __restrict__ edges,
                                                 const float* __restrict__ h2,
                                                 float* __restrict__ outp) {
    __shared__ float acc[256 * 17];
    __shared__ float lse[256];
    const int t = threadIdx.x;
    for (int i = t; i < 256 * 17; i += 256) acc[i] = 0.f;
    __syncthreads();

    const int b    = blockIdx.x;
    const int beg  = bbase[b];
    const int n    = bbase[b + 1] - beg;
    const int lane = t & 63;
    const int w    = t >> 6;           // 4 waves
    const int sub  = lane >> 4;        // 4 edges/wave
    const int c    = lane & 15;
    const int slot = w * 4 + sub;      // 0..15
    const int nmain = n & ~31;

    for (int base = slot; base < nmain; base += 32) {
        int2 E0 = edges[beg + base];
        int2 E1 = edges[beg + base + 16];
        float g0 = h2[(size_t)(E0.x & 0x1FFFF) * N_CLS + c];
        float g1 = h2[(size_t)(E1.x & 0x1FFFF) * N_CLS + c];
        atomicAdd(&acc[(E0.x >> 17) * 17 + c], __int_as_float(E0.y) * g0);
        atomicAdd(&acc[(E1.x >> 17) * 17 + c], __int_as_float(E1.y) * g1);
    }
    for (int j = nmain + slot; j < n; j += 16) {
        int2 E = edges[beg + j];
        float g = h2[(size_t)(E.x & 0x1FFFF) * N_CLS + c];
        atomicAdd(&acc[(E.x >> 17) * 17 + c], __int_as_float(E.y) * g);
    }
    __syncthreads();

    {   // per-row logsumexp (thread = row); stride 17 => conflict-free
        float v[16];
        float m = -1e30f;
        #pragma unroll
        for (int k = 0; k < 16; ++k) { v[k] = acc[t * 17 + k]; m = fmaxf(m, v[k]); }
        float s = 0.f;
        #pragma unroll
        for (int k = 0; k < 16; ++k) s += expf(v[k] - m);
        lse[t] = m + logf(s);
    }
    __syncthreads();

    const int row0 = b << 8;
    const int nf   = min(256, N_NODES - row0) * N_CLS;
    for (int j = t; j < nf; j += 256)
        outp[(size_t)row0 * N_CLS + j] = acc[(j >> 4) * 17 + (j & 15)] - lse[j >> 4];
}

extern "C" void kernel_launch(void* const* d_in, const int* in_sizes, int n_in,
                              void* d_out, int out_size, void* d_ws, size_t ws_size,
                              hipStream_t stream) {
    const float* x        = (const float*)d_in[0];
    const int*   adj_row  = (const int*)d_in[1];
    const int*   adj_col  = (const int*)d_in[2];
    const float* adj_vals = (const float*)d_in[3];
    const float* W1       = (const float*)d_in[4];
    const float* b1       = (const float*)d_in[5];
    const float* W2       = (const float*)d_in[6];
    const float* b2       = (const float*)d_in[7];
    float*       out      = (float*)d_out;

    // Workspace (peak ~52 MB): h0(bf16 12.8M) | h1(25.6M) | edges(12.8M) | meta
    const size_t H0_BYTES = (size_t)N_NODES * N_HID * sizeof(bfraw);
    const size_t H1_BYTES = (size_t)N_NODES * N_HID * sizeof(float);
    const size_t E_BYTES  = (size_t)N_EDGES * sizeof(int2);
    bfraw* h0    = (bfraw*)d_ws;
    float* h1    = (float*)((char*)d_ws + H0_BYTES);
    int2*  edges = (int2*)((char*)h1 + H1_BYTES);
    int*   bcnt  = (int*)((char*)edges + E_BYTES);     // NB
    int*   bbase = bcnt + NB;                          // NB+1
    int*   gcur  = bbase + NB + 1;                     // NB
    float* h2    = (float*)d_ws;                       // reuse h0 region (6.4 MB)

    // --- bucket build ---
    hipMemsetAsync(bcnt, 0, NB * sizeof(int), stream);
    hist_k<<<256, 256, 0, stream>>>(adj_row, bcnt);
    bscan_k<<<1, 512, 0, stream>>>(bcnt, bbase, gcur);
    scatter_k<<<(N_EDGES + CHUNK - 1) / CHUNK, 256, 0, stream>>>(adj_row, adj_col,
                                                                 adj_vals, gcur, edges);

    // --- layer 1 ---
    gemm1_k<<<(N_NODES + 63) / 64, 256, 0, stream>>>(x, W1, b1, h0);
    spmm1_b_k<<<NB, 512, 0, stream>>>(bbase, edges, h0, h1);

    // --- layer 2 ---
    gemm2_k<<<(N_NODES + 63) / 64, 256, 0, stream>>>(h1, W2, b2, h2);
    spmm2_b_k<<<NB, 256, 0, stream>>>(bbase, edges, h2, out);
}

// Round 8
// 377.804 us; speedup vs baseline: 2.9712x; 2.9712x over previous
//
#include <hip/hip_runtime.h>

#define N_NODES 100000
#define N_EDGES 1600000
#define N_FEAT  256
#define N_HID   64
#define N_CLS   16
#define NB      391          // ceil(N_NODES/256) row buckets
#define CHUNK   8192         // edges per scatter block

typedef unsigned short bfraw;
typedef unsigned int uint32;

__device__ __forceinline__ bfraw f2bf(float f) {   // RNE
    union { float f; unsigned int i; } v; v.f = f;
    unsigned int x = v.i;
    return (bfraw)((x + 0x7FFFu + ((x >> 16) & 1u)) >> 16);
}

// ---------------------------------------------------------------------------
// GEMM1: h0[100000][64](bf16) = x[100000][256] @ W1[256][64] + b1
// ---------------------------------------------------------------------------
__global__ __launch_bounds__(256) void gemm1_k(const float* __restrict__ x,
                                               const float* __restrict__ W1,
                                               const float* __restrict__ b1,
                                               bfraw* __restrict__ h0) {
    __shared__ float As[16][64];   // [k][m]
    __shared__ float Bs[16][64];   // [k][n]
    const int bm  = blockIdx.x * 64;
    const int tid = threadIdx.x;
    const int tx = tid & 15;       // n/4
    const int ty = tid >> 4;       // m/4
    const int a_row = tid >> 2;
    const int a_k   = (tid & 3) * 4;
    const int b_k = tid >> 4;
    const int b_n = (tid & 15) * 4;

    const int  arow_g = bm + a_row;
    const bool a_ok   = arow_g < N_NODES;

    float acc[4][4] = {};

    for (int k0 = 0; k0 < N_FEAT; k0 += 16) {
        float4 ar = make_float4(0.f, 0.f, 0.f, 0.f);
        if (a_ok) ar = *(const float4*)(x + (size_t)arow_g * N_FEAT + k0 + a_k);
        float4 br = *(const float4*)(W1 + (size_t)(k0 + b_k) * N_HID + b_n);

        As[a_k + 0][a_row] = ar.x;
        As[a_k + 1][a_row] = ar.y;
        As[a_k + 2][a_row] = ar.z;
        As[a_k + 3][a_row] = ar.w;
        *(float4*)&Bs[b_k][b_n] = br;
        __syncthreads();

        #pragma unroll
        for (int kk = 0; kk < 16; ++kk) {
            float4 av = *(const float4*)&As[kk][ty * 4];
            float4 bv = *(const float4*)&Bs[kk][tx * 4];
            float a[4] = {av.x, av.y, av.z, av.w};
            float b[4] = {bv.x, bv.y, bv.z, bv.w};
            #pragma unroll
            for (int i = 0; i < 4; ++i)
                #pragma unroll
                for (int j = 0; j < 4; ++j)
                    acc[i][j] += a[i] * b[j];
        }
        __syncthreads();
    }

    float bb[4];
    #pragma unroll
    for (int j = 0; j < 4; ++j) bb[j] = b1[tx * 4 + j];

    #pragma unroll
    for (int i = 0; i < 4; ++i) {
        int row = bm + ty * 4 + i;
        if (row < N_NODES) {
            ushort4 o;
            o.x = f2bf(acc[i][0] + bb[0]);
            o.y = f2bf(acc[i][1] + bb[1]);
            o.z = f2bf(acc[i][2] + bb[2]);
            o.w = f2bf(acc[i][3] + bb[3]);
            *(ushort4*)(h0 + (size_t)row * N_HID + tx * 4) = o;
        }
    }
}

// ---------------------------------------------------------------------------
// Bucket histogram (row>>8), LDS-staged
// ---------------------------------------------------------------------------
__global__ __launch_bounds__(256) void hist_k(const int* __restrict__ rowi,
                                              int* __restrict__ bcnt) {
    __shared__ int lh[NB];
    for (int i = threadIdx.x; i < NB; i += 256) lh[i] = 0;
    __syncthreads();
    for (int e = blockIdx.x * 256 + threadIdx.x; e < N_EDGES; e += gridDim.x * 256)
        atomicAdd(&lh[rowi[e] >> 8], 1);
    __syncthreads();
    for (int i = threadIdx.x; i < NB; i += 256) {
        int c = lh[i];
        if (c) atomicAdd(&bcnt[i], c);
    }
}

// exclusive scan of NB bucket counts -> bbase[0..NB], cursors; rp[N]=E
__global__ __launch_bounds__(512) void bscan_k(const int* __restrict__ bcnt,
                                               int* __restrict__ bbase,
                                               int* __restrict__ gcur,
                                               int* __restrict__ rp) {
    __shared__ int s[512];
    int t = threadIdx.x;
    int v = (t < NB) ? bcnt[t] : 0;
    s[t] = v;
    __syncthreads();
    #pragma unroll
    for (int off = 1; off < 512; off <<= 1) {
        int x = (t >= off) ? s[t - off] : 0;
        __syncthreads();
        s[t] += x;
        __syncthreads();
    }
    if (t <= NB) {
        int b = s[t] - v;              // exclusive prefix (v=0 at t==NB)
        bbase[t] = b;
        if (t < NB) gcur[t] = b;
    }
    if (t == 0) rp[N_NODES] = N_EDGES;
}

// ---------------------------------------------------------------------------
// Scatter edges into bucket regions as packed int2 (col | rowlow<<17, val)
// ---------------------------------------------------------------------------
__global__ __launch_bounds__(256) void scatter_k(const int* __restrict__ rowi,
                                                 const int* __restrict__ coli,
                                                 const float* __restrict__ vals,
                                                 int* __restrict__ gcur,
                                                 int2* __restrict__ edges) {
    __shared__ int lh[NB];
    __shared__ int lb[NB];
    const int t  = threadIdx.x;
    const int e0 = blockIdx.x * CHUNK;
    for (int i = t; i < NB; i += 256) lh[i] = 0;
    __syncthreads();
    for (int j = t; j < CHUNK; j += 256) {
        int e = e0 + j;
        if (e < N_EDGES) atomicAdd(&lh[rowi[e] >> 8], 1);
    }
    __syncthreads();
    for (int i = t; i < NB; i += 256) {
        int c = lh[i];
        lb[i] = c ? atomicAdd(&gcur[i], c) : 0;
        lh[i] = 0;                      // reuse as rank counter
    }
    __syncthreads();
    for (int j = t; j < CHUNK; j += 256) {
        int e = e0 + j;
        if (e < N_EDGES) {
            int r  = rowi[e];
            int b  = r >> 8;
            int rk = atomicAdd(&lh[b], 1);
            edges[lb[b] + rk] = make_int2(coli[e] | ((r & 255) << 17),
                                          __float_as_int(vals[e]));
        }
    }
}

// ---------------------------------------------------------------------------
// Per-bucket counting sort -> exact CSR (edges2, rp). One block per bucket;
// all scattered writes land in this bucket's contiguous ~32KB region.
// ---------------------------------------------------------------------------
__global__ __launch_bounds__(256) void sort_k(const int* __restrict__ bbase,
                                              const int2* __restrict__ edges,
                                              int2* __restrict__ edges2,
                                              int* __restrict__ rp) {
    __shared__ int cnt[256];
    __shared__ int pos[256];
    const int t   = threadIdx.x;
    const int b   = blockIdx.x;
    const int beg = bbase[b];
    const int end = bbase[b + 1];

    cnt[t] = 0;
    __syncthreads();
    for (int i = beg + t; i < end; i += 256)
        atomicAdd(&cnt[(edges[i].x >> 17) & 255], 1);
    __syncthreads();

    // exclusive scan of cnt
    int v = cnt[t];
    int s = v;
    #pragma unroll
    for (int off = 1; off < 256; off <<= 1) {
        int y = __shfl_up(s, off, 64);        // partial; do LDS scan instead
        (void)y;
        break;
    }
    // LDS inclusive scan (simple, 256 elems)
    pos[t] = v;
    __syncthreads();
    #pragma unroll
    for (int off = 1; off < 256; off <<= 1) {
        int y = (t >= off) ? pos[t - off] : 0;
        __syncthreads();
        pos[t] += y;
        __syncthreads();
    }
    int excl = pos[t] - v;

    int row = (b << 8) + t;
    if (row < N_NODES) rp[row] = beg + excl;
    __syncthreads();
    pos[t] = excl;                             // cursor
    __syncthreads();

    for (int i = beg + t; i < end; i += 256) {
        int2 E = edges[i];
        int r  = (E.x >> 17) & 255;
        int rk = atomicAdd(&pos[r], 1);
        edges2[beg + rk] = make_int2(E.x & 0x1FFFF, E.y);
    }
}

// ---------------------------------------------------------------------------
// SpMM1 (CSR): h1[row][0:64] = sum val * h0[col][0:64](bf16)
// One wave per row; half-wave per edge (2 edges in flight), bf16x2 loads.
// ---------------------------------------------------------------------------
__global__ __launch_bounds__(256) void spmm1_csr_k(const int* __restrict__ rp,
                                                   const int2* __restrict__ edges2,
                                                   const uint32* __restrict__ h0p,
                                                   float* __restrict__ h1) {
    const int t    = threadIdx.x;
    const int lane = t & 63;
    const int row  = blockIdx.x * 4 + (t >> 6);
    const int half = lane >> 5;          // which edge of a pair
    const int l2   = lane & 31;          // bf16-pair (feature*2) index
    const int beg  = rp[row];
    const int end  = rp[row + 1];

    float ax = 0.f, ay = 0.f;
    int i = beg;
    for (; i + 8 <= end; i += 8) {
        int2 E[4];
        #pragma unroll
        for (int u = 0; u < 4; ++u) E[u] = edges2[i + 2 * u + half];
        uint32 g[4];
        #pragma unroll
        for (int u = 0; u < 4; ++u) g[u] = h0p[(size_t)E[u].x * 32 + l2];
        #pragma unroll
        for (int u = 0; u < 4; ++u) {
            float v = __int_as_float(E[u].y);
            ax += v * __uint_as_float(g[u] << 16);
            ay += v * __uint_as_float(g[u] & 0xFFFF0000u);
        }
    }
    for (; i + 2 <= end; i += 2) {
        int2 E = edges2[i + half];
        uint32 g = h0p[(size_t)E.x * 32 + l2];
        float v = __int_as_float(E.y);
        ax += v * __uint_as_float(g << 16);
        ay += v * __uint_as_float(g & 0xFFFF0000u);
    }
    if (i < end && half == 0) {
        int2 E = edges2[i];
        uint32 g = h0p[(size_t)E.x * 32 + l2];
        float v = __int_as_float(E.y);
        ax += v * __uint_as_float(g << 16);
        ay += v * __uint_as_float(g & 0xFFFF0000u);
    }

    ax += __shfl_xor(ax, 32);
    ay += __shfl_xor(ay, 32);
    if (half == 0)
        *(float2*)(h1 + (size_t)row * N_HID + l2 * 2) = make_float2(ax, ay);
}

// ---------------------------------------------------------------------------
// GEMM2 fused with ReLU: h2[100000][16] = relu(h1) @ W2 + b2   (fp32)
// ---------------------------------------------------------------------------
__global__ __launch_bounds__(256) void gemm2_k(const float* __restrict__ h1,
                                               const float* __restrict__ W2,
                                               const float* __restrict__ b2,
                                               float* __restrict__ h2) {
    __shared__ float Hs[64][65];
    __shared__ float Ws[64 * 16];
    __shared__ float bs[16];
    const int bn  = blockIdx.x * 64;
    const int tid = threadIdx.x;

    *(float4*)&Ws[tid * 4] = *(const float4*)(W2 + tid * 4);
    if (tid < 16) bs[tid] = b2[tid];

    #pragma unroll
    for (int i = 0; i < 4; ++i) {
        int idx  = tid + i * 256;
        int node = idx >> 4;
        int c4   = idx & 15;
        int nr   = bn + node;
        float4 hv = make_float4(0.f, 0.f, 0.f, 0.f);
        if (nr < N_NODES) hv = *(const float4*)(h1 + (size_t)nr * N_HID + c4 * 4);
        Hs[node][c4 * 4 + 0] = fmaxf(hv.x, 0.f);
        Hs[node][c4 * 4 + 1] = fmaxf(hv.y, 0.f);
        Hs[node][c4 * 4 + 2] = fmaxf(hv.z, 0.f);
        Hs[node][c4 * 4 + 3] = fmaxf(hv.w, 0.f);
    }
    __syncthreads();

    const int node = tid >> 2;
    const int c0   = (tid & 3) * 4;
    float a0 = bs[c0 + 0], a1 = bs[c0 + 1], a2 = bs[c0 + 2], a3 = bs[c0 + 3];
    #pragma unroll
    for (int k = 0; k < 64; ++k) {
        float hval = Hs[node][k];
        a0 += hval * Ws[k * 16 + c0 + 0];
        a1 += hval * Ws[k * 16 + c0 + 1];
        a2 += hval * Ws[k * 16 + c0 + 2];
        a3 += hval * Ws[k * 16 + c0 + 3];
    }
    int nr = bn + node;
    if (nr < N_NODES)
        *(float4*)(h2 + (size_t)nr * N_CLS + c0) = make_float4(a0, a1, a2, a3);
}

// ---------------------------------------------------------------------------
// SpMM2 (CSR) fused with log_softmax: 16 lanes per row, 16 rows per block.
// ---------------------------------------------------------------------------
__global__ __launch_bounds__(256) void spmm2_lsm_k(const int* __restrict__ rp,
                                                   const int2* __restrict__ edges2,
                                                   const float* __restrict__ h2,
                                                   float* __restrict__ outp) {
    const int lane = threadIdx.x & 15;
    const int row  = blockIdx.x * 16 + (threadIdx.x >> 4);   // N_NODES = 6250*16
    const int beg = rp[row];
    const int end = rp[row + 1];
    float acc = 0.f;
    int i = beg;
    for (; i + 2 <= end; i += 2) {
        int2 e0 = edges2[i + 0], e1 = edges2[i + 1];
        float g0 = h2[(size_t)e0.x * N_CLS + lane];
        float g1 = h2[(size_t)e1.x * N_CLS + lane];
        acc += __int_as_float(e0.y) * g0;
        acc += __int_as_float(e1.y) * g1;
    }
    if (i < end) {
        int2 e = edges2[i];
        acc += __int_as_float(e.y) * h2[(size_t)e.x * N_CLS + lane];
    }

    float m = acc;
    #pragma unroll
    for (int off = 8; off; off >>= 1) m = fmaxf(m, __shfl_xor(m, off, 16));
    float ex = expf(acc - m);
    float s = ex;
    #pragma unroll
    for (int off = 8; off; off >>= 1) s += __shfl_xor(s, off, 16);
    outp[(size_t)row * N_CLS + lane] = acc - m - logf(s);
}

extern "C" void kernel_launch(void* const* d_in, const int* in_sizes, int n_in,
                              void* d_out, int out_size, void* d_ws, size_t ws_size,
                              hipStream_t stream) {
    const float* x        = (const float*)d_in[0];
    const int*   adj_row  = (const int*)d_in[1];
    const int*   adj_col  = (const int*)d_in[2];
    const float* adj_vals = (const float*)d_in[3];
    const float* W1       = (const float*)d_in[4];
    const float* b1       = (const float*)d_in[5];
    const float* W2       = (const float*)d_in[6];
    const float* b2       = (const float*)d_in[7];
    float*       out      = (float*)d_out;

    // Workspace (~65 MB): h0 bf16 | h1 fp32 | edges | edges2 | meta
    const size_t H0_BYTES = (size_t)N_NODES * N_HID * sizeof(bfraw);   // 12.8 MB
    const size_t H1_BYTES = (size_t)N_NODES * N_HID * sizeof(float);   // 25.6 MB
    const size_t E_BYTES  = (size_t)N_EDGES * sizeof(int2);            // 12.8 MB
    bfraw* h0     = (bfraw*)d_ws;
    float* h1     = (float*)((char*)d_ws + H0_BYTES);
    int2*  edges  = (int2*)((char*)h1 + H1_BYTES);
    int2*  edges2 = (int2*)((char*)edges + E_BYTES);
    int*   bcnt   = (int*)((char*)edges2 + E_BYTES);   // NB
    int*   bbase  = bcnt + NB;                         // NB+1
    int*   gcur   = bbase + NB + 1;                    // NB
    int*   rp     = gcur + NB;                         // N_NODES+1
    float* h2     = (float*)d_ws;                      // reuse h0 region (6.4 MB)

    // --- CSR build via bucket scatter + per-bucket counting sort ---
    hipMemsetAsync(bcnt, 0, NB * sizeof(int), stream);
    hist_k<<<256, 256, 0, stream>>>(adj_row, bcnt);
    bscan_k<<<1, 512, 0, stream>>>(bcnt, bbase, gcur, rp);
    scatter_k<<<(N_EDGES + CHUNK - 1) / CHUNK, 256, 0, stream>>>(adj_row, adj_col,
                                                                 adj_vals, gcur, edges);
    sort_k<<<NB, 256, 0, stream>>>(bbase, edges, edges2, rp);

    // --- layer 1 ---
    gemm1_k<<<(N_NODES + 63) / 64, 256, 0, stream>>>(x, W1, b1, h0);
    spmm1_csr_k<<<N_NODES / 4, 256, 0, stream>>>(rp, edges2, (const uint32*)h0, h1);

    // --- layer 2 ---
    gemm2_k<<<(N_NODES + 63) / 64, 256, 0, stream>>>(h1, W2, b2, h2);
    spmm2_lsm_k<<<N_NODES / 16, 256, 0, stream>>>(rp, edges2, h2, out);
}

// Round 9
// 368.469 us; speedup vs baseline: 3.0465x; 1.0253x over previous
//
#include <hip/hip_runtime.h>

#define N_NODES 100000
#define N_EDGES 1600000
#define N_FEAT  256
#define N_HID   64
#define N_CLS   16
#define NB      391          // ceil(N_NODES/256) row buckets
#define CHUNK   8192         // edges per scatter block

typedef unsigned short bfraw;
typedef unsigned int uint32;

typedef __attribute__((ext_vector_type(8))) short  bf16x8;
typedef __attribute__((ext_vector_type(4))) float  f32x4;

__device__ __forceinline__ bfraw f2bf(float f) {   // RNE
    union { float f; unsigned int i; } v; v.f = f;
    unsigned int x = v.i;
    return (bfraw)((x + 0x7FFFu + ((x >> 16) & 1u)) >> 16);
}

// ---------------------------------------------------------------------------
// Pack W1 (fp32 [256][64]) into B-fragment-order bf16 table:
// w1f[((k>>3)*64 + n)*8 + (k&7)] = bf16(W1[k][n])
// ---------------------------------------------------------------------------
__global__ __launch_bounds__(256) void w1cvt_k(const float* __restrict__ W1,
                                               bfraw* __restrict__ w1f) {
    int i = blockIdx.x * 256 + threadIdx.x;          // 16384 total
    int k = i >> 6, n = i & 63;
    w1f[((size_t)((k >> 3) * 64 + n) << 3) + (k & 7)] = f2bf(W1[i]);
}

// ---------------------------------------------------------------------------
// GEMM1 via MFMA, no LDS: h0[100000][64](bf16) = x @ W1 + b1
// Block: 256 thr = 4 waves; wave = 16 rows x 64 cols; 8 K-steps of 32.
// A frag: A[m=lane&15][k=quad*8+j] loaded from x (fp32->bf16 in-register).
// B frag: from w1f table (L2-resident).  C/D: col=lane&15, row=quad*4+reg.
// ---------------------------------------------------------------------------
__global__ __launch_bounds__(256) void gemm1_k(const float* __restrict__ x,
                                               const bfraw* __restrict__ w1f,
                                               const float* __restrict__ b1,
                                               bfraw* __restrict__ h0) {
    const int t    = threadIdx.x;
    const int w    = t >> 6;
    const int lane = t & 63;
    const int q    = lane >> 4;
    const int m    = lane & 15;

    const int row  = blockIdx.x * 64 + w * 16 + m;
    const int srow = row < N_NODES ? row : N_NODES - 1;
    const float* xp = x + (size_t)srow * N_FEAT + q * 8;
    const bf16x8* w1v = (const bf16x8*)w1f;

    f32x4 acc[4];
    #pragma unroll
    for (int nt = 0; nt < 4; ++nt) acc[nt] = (f32x4){0.f, 0.f, 0.f, 0.f};

    #pragma unroll
    for (int s = 0; s < 8; ++s) {
        float4 a0 = *(const float4*)(xp + s * 32);
        float4 a1 = *(const float4*)(xp + s * 32 + 4);
        bf16x8 af;
        af[0] = (short)f2bf(a0.x); af[1] = (short)f2bf(a0.y);
        af[2] = (short)f2bf(a0.z); af[3] = (short)f2bf(a0.w);
        af[4] = (short)f2bf(a1.x); af[5] = (short)f2bf(a1.y);
        af[6] = (short)f2bf(a1.z); af[7] = (short)f2bf(a1.w);
        const int g = s * 4 + q;                 // k-group (k = g*8)
        #pragma unroll
        for (int nt = 0; nt < 4; ++nt) {
            bf16x8 bf_ = w1v[g * 64 + nt * 16 + m];
            acc[nt] = __builtin_amdgcn_mfma_f32_16x16x32_bf16(af, bf_, acc[nt], 0, 0, 0);
        }
    }

    float bb[4];
    #pragma unroll
    for (int nt = 0; nt < 4; ++nt) bb[nt] = b1[nt * 16 + m];

    const int orow0 = blockIdx.x * 64 + w * 16 + q * 4;
    #pragma unroll
    for (int r = 0; r < 4; ++r) {
        int orow = orow0 + r;
        if (orow < N_NODES) {
            bfraw* op = h0 + (size_t)orow * N_HID + m;
            #pragma unroll
            for (int nt = 0; nt < 4; ++nt)
                op[nt * 16] = f2bf(acc[nt][r] + bb[nt]);
        }
    }
}

// ---------------------------------------------------------------------------
// Bucket histogram (row>>8), LDS-staged
// ---------------------------------------------------------------------------
__global__ __launch_bounds__(256) void hist_k(const int* __restrict__ rowi,
                                              int* __restrict__ bcnt) {
    __shared__ int lh[NB];
    for (int i = threadIdx.x; i < NB; i += 256) lh[i] = 0;
    __syncthreads();
    for (int e = blockIdx.x * 256 + threadIdx.x; e < N_EDGES; e += gridDim.x * 256)
        atomicAdd(&lh[rowi[e] >> 8], 1);
    __syncthreads();
    for (int i = threadIdx.x; i < NB; i += 256) {
        int c = lh[i];
        if (c) atomicAdd(&bcnt[i], c);
    }
}

// exclusive scan of NB bucket counts -> bbase[0..NB], cursors; rp[N]=E
__global__ __launch_bounds__(512) void bscan_k(const int* __restrict__ bcnt,
                                               int* __restrict__ bbase,
                                               int* __restrict__ gcur,
                                               int* __restrict__ rp) {
    __shared__ int s[512];
    int t = threadIdx.x;
    int v = (t < NB) ? bcnt[t] : 0;
    s[t] = v;
    __syncthreads();
    #pragma unroll
    for (int off = 1; off < 512; off <<= 1) {
        int x = (t >= off) ? s[t - off] : 0;
        __syncthreads();
        s[t] += x;
        __syncthreads();
    }
    if (t <= NB) {
        int b = s[t] - v;              // exclusive prefix (v=0 at t==NB)
        bbase[t] = b;
        if (t < NB) gcur[t] = b;
    }
    if (t == 0) rp[N_NODES] = N_EDGES;
}

// ---------------------------------------------------------------------------
// Scatter edges into bucket regions as packed int2 (col | rowlow<<17, val)
// ---------------------------------------------------------------------------
__global__ __launch_bounds__(256) void scatter_k(const int* __restrict__ rowi,
                                                 const int* __restrict__ coli,
                                                 const float* __restrict__ vals,
                                                 int* __restrict__ gcur,
                                                 int2* __restrict__ edges) {
    __shared__ int lh[NB];
    __shared__ int lb[NB];
    const int t  = threadIdx.x;
    const int e0 = blockIdx.x * CHUNK;
    for (int i = t; i < NB; i += 256) lh[i] = 0;
    __syncthreads();
    for (int j = t; j < CHUNK; j += 256) {
        int e = e0 + j;
        if (e < N_EDGES) atomicAdd(&lh[rowi[e] >> 8], 1);
    }
    __syncthreads();
    for (int i = t; i < NB; i += 256) {
        int c = lh[i];
        lb[i] = c ? atomicAdd(&gcur[i], c) : 0;
        lh[i] = 0;                      // reuse as rank counter
    }
    __syncthreads();
    for (int j = t; j < CHUNK; j += 256) {
        int e = e0 + j;
        if (e < N_EDGES) {
            int r  = rowi[e];
            int b  = r >> 8;
            int rk = atomicAdd(&lh[b], 1);
            edges[lb[b] + rk] = make_int2(coli[e] | ((r & 255) << 17),
                                          __float_as_int(vals[e]));
        }
    }
}

// ---------------------------------------------------------------------------
// Per-bucket counting sort -> exact CSR (edges2, rp). One block per bucket.
// ---------------------------------------------------------------------------
__global__ __launch_bounds__(256) void sort_k(const int* __restrict__ bbase,
                                              const int2* __restrict__ edges,
                                              int2* __restrict__ edges2,
                                              int* __restrict__ rp) {
    __shared__ int cnt[256];
    __shared__ int pos[256];
    const int t   = threadIdx.x;
    const int b   = blockIdx.x;
    const int beg = bbase[b];
    const int end = bbase[b + 1];

    cnt[t] = 0;
    __syncthreads();
    for (int i = beg + t; i < end; i += 256)
        atomicAdd(&cnt[(edges[i].x >> 17) & 255], 1);
    __syncthreads();

    int v = cnt[t];
    pos[t] = v;
    __syncthreads();
    #pragma unroll
    for (int off = 1; off < 256; off <<= 1) {
        int y = (t >= off) ? pos[t - off] : 0;
        __syncthreads();
        pos[t] += y;
        __syncthreads();
    }
    int excl = pos[t] - v;

    int row = (b << 8) + t;
    if (row < N_NODES) rp[row] = beg + excl;
    __syncthreads();
    pos[t] = excl;                             // cursor
    __syncthreads();

    for (int i = beg + t; i < end; i += 256) {
        int2 E = edges[i];
        int r  = (E.x >> 17) & 255;
        int rk = atomicAdd(&pos[r], 1);
        edges2[beg + rk] = make_int2(E.x & 0x1FFFF, E.y);
    }
}

// ---------------------------------------------------------------------------
// SpMM1 (CSR): h1[row][0:64] = sum val * h0[col][0:64](bf16)
// One wave per row; half-wave per edge (2 edges in flight), bf16x2 loads.
// ---------------------------------------------------------------------------
__global__ __launch_bounds__(256) void spmm1_csr_k(const int* __restrict__ rp,
                                                   const int2* __restrict__ edges2,
                                                   const uint32* __restrict__ h0p,
                                                   float* __restrict__ h1) {
    const int t    = threadIdx.x;
    const int lane = t & 63;
    const int row  = blockIdx.x * 4 + (t >> 6);
    const int half = lane >> 5;          // which edge of a pair
    const int l2   = lane & 31;          // bf16-pair (feature*2) index
    const int beg  = rp[row];
    const int end  = rp[row + 1];

    float ax = 0.f, ay = 0.f;
    int i = beg;
    for (; i + 8 <= end; i += 8) {
        int2 E[4];
        #pragma unroll
        for (int u = 0; u < 4; ++u) E[u] = edges2[i + 2 * u + half];
        uint32 g[4];
        #pragma unroll
        for (int u = 0; u < 4; ++u) g[u] = h0p[(size_t)E[u].x * 32 + l2];
        #pragma unroll
        for (int u = 0; u < 4; ++u) {
            float v = __int_as_float(E[u].y);
            ax += v * __uint_as_float(g[u] << 16);
            ay += v * __uint_as_float(g[u] & 0xFFFF0000u);
        }
    }
    for (; i + 2 <= end; i += 2) {
        int2 E = edges2[i + half];
        uint32 g = h0p[(size_t)E.x * 32 + l2];
        float v = __int_as_float(E.y);
        ax += v * __uint_as_float(g << 16);
        ay += v * __uint_as_float(g & 0xFFFF0000u);
    }
    if (i < end && half == 0) {
        int2 E = edges2[i];
        uint32 g = h0p[(size_t)E.x * 32 + l2];
        float v = __int_as_float(E.y);
        ax += v * __uint_as_float(g << 16);
        ay += v * __uint_as_float(g & 0xFFFF0000u);
    }

    ax += __shfl_xor(ax, 32);
    ay += __shfl_xor(ay, 32);
    if (half == 0)
        *(float2*)(h1 + (size_t)row * N_HID + l2 * 2) = make_float2(ax, ay);
}

// ---------------------------------------------------------------------------
// GEMM2 fused with ReLU: h2[100000][16] = relu(h1) @ W2 + b2   (fp32)
// ---------------------------------------------------------------------------
__global__ __launch_bounds__(256) void gemm2_k(const float* __restrict__ h1,
                                               const float* __restrict__ W2,
                                               const float* __restrict__ b2,
                                               float* __restrict__ h2) {
    __shared__ float Hs[64][65];
    __shared__ float Ws[64 * 16];
    __shared__ float bs[16];
    const int bn  = blockIdx.x * 64;
    const int tid = threadIdx.x;

    *(float4*)&Ws[tid * 4] = *(const float4*)(W2 + tid * 4);
    if (tid < 16) bs[tid] = b2[tid];

    #pragma unroll
    for (int i = 0; i < 4; ++i) {
        int idx  = tid + i * 256;
        int node = idx >> 4;
        int c4   = idx & 15;
        int nr   = bn + node;
        float4 hv = make_float4(0.f, 0.f, 0.f, 0.f);
        if (nr < N_NODES) hv = *(const float4*)(h1 + (size_t)nr * N_HID + c4 * 4);
        Hs[node][c4 * 4 + 0] = fmaxf(hv.x, 0.f);
        Hs[node][c4 * 4 + 1] = fmaxf(hv.y, 0.f);
        Hs[node][c4 * 4 + 2] = fmaxf(hv.z, 0.f);
        Hs[node][c4 * 4 + 3] = fmaxf(hv.w, 0.f);
    }
    __syncthreads();

    const int node = tid >> 2;
    const int c0   = (tid & 3) * 4;
    float a0 = bs[c0 + 0], a1 = bs[c0 + 1], a2 = bs[c0 + 2], a3 = bs[c0 + 3];
    #pragma unroll
    for (int k = 0; k < 64; ++k) {
        float hval = Hs[node][k];
        a0 += hval * Ws[k * 16 + c0 + 0];
        a1 += hval * Ws[k * 16 + c0 + 1];
        a2 += hval * Ws[k * 16 + c0 + 2];
        a3 += hval * Ws[k * 16 + c0 + 3];
    }
    int nr = bn + node;
    if (nr < N_NODES)
        *(float4*)(h2 + (size_t)nr * N_CLS + c0) = make_float4(a0, a1, a2, a3);
}

// ---------------------------------------------------------------------------
// SpMM2 (CSR) fused with log_softmax: 16 lanes per row, 16 rows per block.
// ---------------------------------------------------------------------------
__global__ __launch_bounds__(256) void spmm2_lsm_k(const int* __restrict__ rp,
                                                   const int2* __restrict__ edges2,
                                                   const float* __restrict__ h2,
                                                   float* __restrict__ outp) {
    const int lane = threadIdx.x & 15;
    const int row  = blockIdx.x * 16 + (threadIdx.x >> 4);   // N_NODES = 6250*16
    const int beg = rp[row];
    const int end = rp[row + 1];
    float acc = 0.f;
    int i = beg;
    for (; i + 2 <= end; i += 2) {
        int2 e0 = edges2[i + 0], e1 = edges2[i + 1];
        float g0 = h2[(size_t)e0.x * N_CLS + lane];
        float g1 = h2[(size_t)e1.x * N_CLS + lane];
        acc += __int_as_float(e0.y) * g0;
        acc += __int_as_float(e1.y) * g1;
    }
    if (i < end) {
        int2 e = edges2[i];
        acc += __int_as_float(e.y) * h2[(size_t)e.x * N_CLS + lane];
    }

    float m = acc;
    #pragma unroll
    for (int off = 8; off; off >>= 1) m = fmaxf(m, __shfl_xor(m, off, 16));
    float ex = expf(acc - m);
    float s = ex;
    #pragma unroll
    for (int off = 8; off; off >>= 1) s += __shfl_xor(s, off, 16);
    outp[(size_t)row * N_CLS + lane] = acc - m - logf(s);
}

extern "C" void kernel_launch(void* const* d_in, const int* in_sizes, int n_in,
                              void* d_out, int out_size, void* d_ws, size_t ws_size,
                              hipStream_t stream) {
    const float* x        = (const float*)d_in[0];
    const int*   adj_row  = (const int*)d_in[1];
    const int*   adj_col  = (const int*)d_in[2];
    const float* adj_vals = (const float*)d_in[3];
    const float* W1       = (const float*)d_in[4];
    const float* b1       = (const float*)d_in[5];
    const float* W2       = (const float*)d_in[6];
    const float* b2       = (const float*)d_in[7];
    float*       out      = (float*)d_out;

    // Workspace (~65 MB): h0 bf16 | h1 fp32 | edges | edges2 | meta | w1f
    const size_t H0_BYTES = (size_t)N_NODES * N_HID * sizeof(bfraw);   // 12.8 MB
    const size_t H1_BYTES = (size_t)N_NODES * N_HID * sizeof(float);   // 25.6 MB
    const size_t E_BYTES  = (size_t)N_EDGES * sizeof(int2);            // 12.8 MB
    bfraw* h0     = (bfraw*)d_ws;
    float* h1     = (float*)((char*)d_ws + H0_BYTES);
    int2*  edges  = (int2*)((char*)h1 + H1_BYTES);
    int2*  edges2 = (int2*)((char*)edges + E_BYTES);
    int*   bcnt   = (int*)((char*)edges2 + E_BYTES);   // NB
    int*   bbase  = bcnt + NB;                         // NB+1
    int*   gcur   = bbase + NB + 1;                    // NB
    int*   rp     = gcur + NB;                         // N_NODES+1
    bfraw* w1f    = (bfraw*)(rp + N_NODES + 1);        // 16384 bf16 (32 KB)
    float* h2     = (float*)d_ws;                      // reuse h0 region (6.4 MB)

    // --- CSR build via bucket scatter + per-bucket counting sort ---
    hipMemsetAsync(bcnt, 0, NB * sizeof(int), stream);
    hist_k<<<256, 256, 0, stream>>>(adj_row, bcnt);
    bscan_k<<<1, 512, 0, stream>>>(bcnt, bbase, gcur, rp);
    scatter_k<<<(N_EDGES + CHUNK - 1) / CHUNK, 256, 0, stream>>>(adj_row, adj_col,
                                                                 adj_vals, gcur, edges);
    sort_k<<<NB, 256, 0, stream>>>(bbase, edges, edges2, rp);

    // --- layer 1 ---
    w1cvt_k<<<64, 256, 0, stream>>>(W1, w1f);
    gemm1_k<<<(N_NODES + 63) / 64, 256, 0, stream>>>(x, w1f, b1, h0);
    spmm1_csr_k<<<N_NODES / 4, 256, 0, stream>>>(rp, edges2, (const uint32*)h0, h1);

    // --- layer 2 ---
    gemm2_k<<<(N_NODES + 63) / 64, 256, 0, stream>>>(h1, W2, b2, h2);
    spmm2_lsm_k<<<N_NODES / 16, 256, 0, stream>>>(rp, edges2, h2, out);
}